// Round 1
// 198.370 us; speedup vs baseline: 1.0529x; 1.0529x over previous
//
#include <hip/hip_runtime.h>
#include <hip/hip_bf16.h>
#include <stdint.h>

#define DOUT 1024
#define NMAX 16384

typedef __attribute__((ext_vector_type(8))) short short8;
typedef __attribute__((ext_vector_type(4))) float floatx4;

__device__ __forceinline__ unsigned short f2bf(float f) {
  union { float f; uint32_t u; } v;
  v.f = f;
  return (unsigned short)((v.u + 0x7FFFu + ((v.u >> 16) & 1u)) >> 16);  // RNE
}

// pack 8 fp32 -> 8 bf16 (RNE) using HW packed cvt
__device__ __forceinline__ short8 cvt8(float4 a, float4 b) {
  __hip_bfloat162 p0 = __float22bfloat162_rn(make_float2(a.x, a.y));
  __hip_bfloat162 p1 = __float22bfloat162_rn(make_float2(a.z, a.w));
  __hip_bfloat162 p2 = __float22bfloat162_rn(make_float2(b.x, b.y));
  __hip_bfloat162 p3 = __float22bfloat162_rn(make_float2(b.z, b.w));
  union { __hip_bfloat162 h[4]; short8 s; } u;
  u.h[0] = p0; u.h[1] = p1; u.h[2] = p2; u.h[3] = p3;
  return u.s;
}

// ---------------------------------------------------------------------------
// classify tokens (blocks 0..63) + convert weights to bf16 (blocks 64..).
// ---------------------------------------------------------------------------
__global__ __launch_bounds__(256) void classify_cvt_kernel(
    const int* __restrict__ idx, int* __restrict__ cnt,
    int* __restrict__ bucket, int* __restrict__ blocal, int N,
    const float* __restrict__ w0, const float* __restrict__ w1,
    const float* __restrict__ w2, unsigned short* __restrict__ wb0,
    unsigned short* __restrict__ wb1, unsigned short* __restrict__ wb2) {
  if (blockIdx.x < 64) {
    int n = blockIdx.x * 256 + threadIdx.x;
    int lane = threadIdx.x & 63;
    int c = -1, v = 0;
    if (n < N) {
      v = idx[n];
      c = (v < 20000) ? 0 : ((v < 40000) ? 1 : 2);
    }
#pragma unroll
    for (int k = 0; k < 3; ++k) {
      unsigned long long m = __ballot(c == k);
      if (c == k) {
        int leader = __ffsll((unsigned long long)m) - 1;
        int base = 0;
        if (lane == leader) base = atomicAdd(&cnt[k], (int)__popcll(m));
        base = __shfl(base, leader);
        int rank = (int)__popcll(m & ((1ull << (unsigned)lane) - 1ull));
        int lo = (k == 0) ? 0 : (k == 1) ? 20000 : 40000;
        bucket[k * NMAX + base + rank] = n;
        blocal[k * NMAX + base + rank] = v - lo;
      }
    }
  } else {
    int i = (blockIdx.x - 64) * 256 + threadIdx.x;
    if (i >= 344064) return;
    const float4* src;
    ushort4* dst;
    if (i < 262144) {            // w0: 1024x1024
      src = (const float4*)w0 + i;
      dst = (ushort4*)wb0 + i;
    } else if (i < 327680) {     // w1: 1024x256
      src = (const float4*)w1 + (i - 262144);
      dst = (ushort4*)wb1 + (i - 262144);
    } else {                     // w2: 1024x64
      src = (const float4*)w2 + (i - 327680);
      dst = (ushort4*)wb2 + (i - 327680);
    }
    float4 v = *src;
    ushort4 o;
    o.x = f2bf(v.x); o.y = f2bf(v.y); o.z = f2bf(v.z); o.w = f2bf(v.w);
    *dst = o;
  }
}

// ---------------------------------------------------------------------------
// Gather bucketed embedding rows -> packed bf16 A matrices.
//   Abf layout: [cnt0 x 1024][cnt1 x 256][cnt2 x 64] (+128-row slack)
// Each thread copies 16 elems: 4x float4 read -> 2x short8 write.
//   c0: 64 thr/row, 4 rows/blk, blocks [0,4096)
//   c1: 16 thr/row, 16 rows/blk, blocks [4096,5120)
//   c2:  4 thr/row, 64 rows/blk, blocks [5120,5376)
// ---------------------------------------------------------------------------
__global__ __launch_bounds__(256) void gather_kernel(
    const float* __restrict__ emb0, const float* __restrict__ emb1,
    const float* __restrict__ emb2, const int* __restrict__ cnt,
    const int* __restrict__ blocal, unsigned short* __restrict__ Abf) {
  const int b = blockIdx.x;
  const int c0 = cnt[0], c1 = cnt[1], c2 = cnt[2];
  const float* emb;
  const int* bl;
  int H, count, baseRow, lg;
  size_t off;
  if (b < 4096) {
    emb = emb0; bl = blocal; H = 1024; count = c0; off = 0;
    baseRow = b * 4; lg = 6;
  } else if (b < 5120) {
    emb = emb1; bl = blocal + NMAX; H = 256; count = c1;
    off = (size_t)c0 * 1024; baseRow = (b - 4096) * 16; lg = 4;
  } else {
    emb = emb2; bl = blocal + 2 * NMAX; H = 64; count = c2;
    off = (size_t)c0 * 1024 + (size_t)c1 * 256; baseRow = (b - 5120) * 64; lg = 2;
  }
  const int tid = threadIdx.x;
  const int r = baseRow + (tid >> lg);
  if (r >= count) return;
  const int e = (tid & ((1 << lg) - 1)) * 16;
  const float* src = emb + (size_t)bl[r] * H + e;
  unsigned short* d = Abf + off + (size_t)r * H + e;
  float4 v0 = ((const float4*)src)[0];
  float4 v1 = ((const float4*)src)[1];
  float4 v2 = ((const float4*)src)[2];
  float4 v3 = ((const float4*)src)[3];
  *(short8*)d = cvt8(v0, v1);
  *(short8*)(d + 8) = cvt8(v2, v3);
}

// ---------------------------------------------------------------------------
// m97-structure bf16 MFMA GEMM on the packed A.
// 128x128 tile, BK=64 (2x32 sub-tiles), 4 waves (2x2), acc[4][4]/wave.
// A and B both staged via global_load_lds width=16 (linear LDS layout).
// Epilogue scatters rows to out[tok][*].
// ---------------------------------------------------------------------------
template <int H>
__device__ __forceinline__ void gemm_body(
    const unsigned short* __restrict__ A, const unsigned short* __restrict__ B,
    int count, const int* __restrict__ bucket, float* __restrict__ out,
    unsigned short* As, unsigned short* Bs, int* rowTok) {
  const int m0 = blockIdx.y * 128;
  if (m0 >= count) return;
  const int n0 = blockIdx.x * 128;

  const int tid = threadIdx.x;
  const int wave = tid >> 6;
  const int lane = tid & 63;
  const int quad = lane >> 4;
  const int l16 = lane & 15;
  const int wm = wave & 1;   // m-half (64 rows)
  const int wn = wave >> 1;  // n-half (64 cols)

  if (tid < 128) {
    int m = m0 + tid;
    rowTok[tid] = (m < count) ? bucket[m] : -1;
  }

  floatx4 acc[4][4];
#pragma unroll
  for (int i = 0; i < 4; ++i)
#pragma unroll
    for (int j = 0; j < 4; ++j) acc[i][j] = (floatx4){0.f, 0.f, 0.f, 0.f};

  const char* Ab = (const char*)A;
  const char* Bb = (const char*)B;
  const int row = tid >> 2;  // 0..63
  const int ck = tid & 3;    // 16B chunk within 64B sub-tile row

  for (int k0 = 0; k0 < H; k0 += 64) {
    __syncthreads();
    // stage A and B: 2 k-sub-tiles x 2 row-halves each, wave-uniform LDS base
#pragma unroll
    for (int t = 0; t < 2; ++t)
#pragma unroll
      for (int p = 0; p < 2; ++p) {
        const void* ga =
            Ab + ((size_t)(m0 + p * 64 + row) * H + k0 + t * 32) * 2 + ck * 16;
        void* la = (char*)As + (t * 8192 + p * 4096 + wave * 1024);
        __builtin_amdgcn_global_load_lds(
            (const __attribute__((address_space(1))) void*)ga,
            (__attribute__((address_space(3))) void*)la, 16, 0, 0);
        const void* gb =
            Bb + ((size_t)(n0 + p * 64 + row) * H + k0 + t * 32) * 2 + ck * 16;
        void* lb = (char*)Bs + (t * 8192 + p * 4096 + wave * 1024);
        __builtin_amdgcn_global_load_lds(
            (const __attribute__((address_space(1))) void*)gb,
            (__attribute__((address_space(3))) void*)lb, 16, 0, 0);
      }
    __syncthreads();

#pragma unroll
    for (int t = 0; t < 2; ++t) {
      short8 af[4], bf[4];
#pragma unroll
      for (int mi = 0; mi < 4; ++mi)
        af[mi] = *(const short8*)&As[t * 4096 + (wm * 64 + mi * 16 + l16) * 32 + quad * 8];
#pragma unroll
      for (int ni = 0; ni < 4; ++ni)
        bf[ni] = *(const short8*)&Bs[t * 4096 + (wn * 64 + ni * 16 + l16) * 32 + quad * 8];
#pragma unroll
      for (int mi = 0; mi < 4; ++mi)
#pragma unroll
        for (int ni = 0; ni < 4; ++ni)
          acc[mi][ni] = __builtin_amdgcn_mfma_f32_16x16x32_bf16(
              af[mi], bf[ni], acc[mi][ni], 0, 0, 0);
    }
  }

  // epilogue: scatter rows to out[tok][*]  (C/D: col=lane&15, row=quad*4+reg)
  const int colBase = n0 + wn * 64 + l16;
#pragma unroll
  for (int mi = 0; mi < 4; ++mi) {
#pragma unroll
    for (int r = 0; r < 4; ++r) {
      int tok = rowTok[wm * 64 + mi * 16 + quad * 4 + r];
      if (tok >= 0) {
        float* o = out + (size_t)tok * DOUT + colBase;
#pragma unroll
        for (int ni = 0; ni < 4; ++ni) o[ni * 16] = acc[mi][ni][r];
      }
    }
  }
}

__global__ __launch_bounds__(256) void gemm_bucketed(
    const unsigned short* __restrict__ Abf,
    const unsigned short* __restrict__ wb0,
    const unsigned short* __restrict__ wb1,
    const unsigned short* __restrict__ wb2, const int* __restrict__ cnt,
    const int* __restrict__ bucket, float* __restrict__ out) {
  __shared__ __align__(16) unsigned short As[2 * 128 * 32];
  __shared__ __align__(16) unsigned short Bs[2 * 128 * 32];
  __shared__ int rowTok[128];

  const int z = blockIdx.z;
  const int c0 = cnt[0];
  const int c1 = cnt[1];
  if (z == 0)
    gemm_body<1024>(Abf, wb0, c0, bucket, out, As, Bs, rowTok);
  else if (z == 1)
    gemm_body<256>(Abf + (size_t)c0 * 1024, wb1, c1, bucket + NMAX, out, As,
                   Bs, rowTok);
  else
    gemm_body<64>(Abf + (size_t)c0 * 1024 + (size_t)c1 * 256, wb2, cnt[2],
                  bucket + 2 * NMAX, out, As, Bs, rowTok);
}

extern "C" void kernel_launch(void* const* d_in, const int* in_sizes, int n_in,
                              void* d_out, int out_size, void* d_ws, size_t ws_size,
                              hipStream_t stream) {
  const int* idx = (const int*)d_in[0];
  const float* emb0 = (const float*)d_in[1];
  const float* w0 = (const float*)d_in[2];
  const float* emb1 = (const float*)d_in[3];
  const float* w1 = (const float*)d_in[4];
  const float* emb2 = (const float*)d_in[5];
  const float* w2 = (const float*)d_in[6];
  float* out = (float*)d_out;
  const int N = in_sizes[0];  // 16384

  // ---- workspace layout ----
  char* ws = (char*)d_ws;
  int* cnt = (int*)ws;                              // 64 B
  int* bucket = (int*)(ws + 1024);                  // 3*NMAX ints
  int* blocal = bucket + 3 * NMAX;                  // 3*NMAX ints
  size_t off = 1024 + (size_t)6 * NMAX * 4;
  off = (off + 255) & ~(size_t)255;
  unsigned short* wb0 = (unsigned short*)(ws + off); off += (size_t)DOUT * 1024 * 2;
  unsigned short* wb1 = (unsigned short*)(ws + off); off += (size_t)DOUT * 256 * 2;
  unsigned short* wb2 = (unsigned short*)(ws + off); off += (size_t)DOUT * 64 * 2;
  off = (off + 255) & ~(size_t)255;
  unsigned short* Abf = (unsigned short*)(ws + off);
  off += (size_t)(NMAX + 128) * 1024 * 2;  // packed A + tile slack (~33.8 MB)

  hipMemsetAsync(cnt, 0, 16 * sizeof(int), stream);

  // classify (64 blocks) + weight cvt (1344 blocks)
  classify_cvt_kernel<<<64 + 1344, 256, 0, stream>>>(
      idx, cnt, bucket, blocal, N, w0, w1, w2, wb0, wb1, wb2);

  // gather bucketed emb rows -> packed bf16 A
  gather_kernel<<<5376, 256, 0, stream>>>(emb0, emb1, emb2, cnt, blocal, Abf);

  // clean bf16 GEMM per cluster: z = cluster
  dim3 grid(DOUT / 128, NMAX / 128, 3);
  gemm_bucketed<<<grid, 256, 0, stream>>>(Abf, wb0, wb1, wb2, cnt, bucket, out);
}

// Round 2
// 197.695 us; speedup vs baseline: 1.0565x; 1.0034x over previous
//
#include <hip/hip_runtime.h>
#include <hip/hip_bf16.h>
#include <stdint.h>

#define DOUT 1024
#define NMAX 16384

#define BM 256
#define BN 128
#define LDSBUF 49152   // per K-tile buffer: A 32768 B + B 16384 B
#define BOFFS 32768    // B region offset within a buffer

typedef __attribute__((ext_vector_type(8))) short short8;
typedef __attribute__((ext_vector_type(4))) float floatx4;

__device__ __forceinline__ unsigned short f2bf(float f) {
  union { float f; uint32_t u; } v;
  v.f = f;
  return (unsigned short)((v.u + 0x7FFFu + ((v.u >> 16) & 1u)) >> 16);  // RNE
}

// pack 8 fp32 -> 8 bf16 (RNE) using HW packed cvt
__device__ __forceinline__ short8 cvt8(float4 a, float4 b) {
  __hip_bfloat162 p0 = __float22bfloat162_rn(make_float2(a.x, a.y));
  __hip_bfloat162 p1 = __float22bfloat162_rn(make_float2(a.z, a.w));
  __hip_bfloat162 p2 = __float22bfloat162_rn(make_float2(b.x, b.y));
  __hip_bfloat162 p3 = __float22bfloat162_rn(make_float2(b.z, b.w));
  union { __hip_bfloat162 h[4]; short8 s; } u;
  u.h[0] = p0; u.h[1] = p1; u.h[2] = p2; u.h[3] = p3;
  return u.s;
}

// ---------------------------------------------------------------------------
// classify tokens (blocks 0..63) + convert weights to bf16 (blocks 64..).
// ---------------------------------------------------------------------------
__global__ __launch_bounds__(256) void classify_cvt_kernel(
    const int* __restrict__ idx, int* __restrict__ cnt,
    int* __restrict__ bucket, int* __restrict__ blocal, int N,
    const float* __restrict__ w0, const float* __restrict__ w1,
    const float* __restrict__ w2, unsigned short* __restrict__ wb0,
    unsigned short* __restrict__ wb1, unsigned short* __restrict__ wb2) {
  if (blockIdx.x < 64) {
    int n = blockIdx.x * 256 + threadIdx.x;
    int lane = threadIdx.x & 63;
    int c = -1, v = 0;
    if (n < N) {
      v = idx[n];
      c = (v < 20000) ? 0 : ((v < 40000) ? 1 : 2);
    }
#pragma unroll
    for (int k = 0; k < 3; ++k) {
      unsigned long long m = __ballot(c == k);
      if (c == k) {
        int leader = __ffsll((unsigned long long)m) - 1;
        int base = 0;
        if (lane == leader) base = atomicAdd(&cnt[k], (int)__popcll(m));
        base = __shfl(base, leader);
        int rank = (int)__popcll(m & ((1ull << (unsigned)lane) - 1ull));
        int lo = (k == 0) ? 0 : (k == 1) ? 20000 : 40000;
        bucket[k * NMAX + base + rank] = n;
        blocal[k * NMAX + base + rank] = v - lo;
      }
    }
  } else {
    int i = (blockIdx.x - 64) * 256 + threadIdx.x;
    if (i >= 344064) return;
    const float4* src;
    ushort4* dst;
    if (i < 262144) {            // w0: 1024x1024
      src = (const float4*)w0 + i;
      dst = (ushort4*)wb0 + i;
    } else if (i < 327680) {     // w1: 1024x256
      src = (const float4*)w1 + (i - 262144);
      dst = (ushort4*)wb1 + (i - 262144);
    } else {                     // w2: 1024x64
      src = (const float4*)w2 + (i - 327680);
      dst = (ushort4*)wb2 + (i - 327680);
    }
    float4 v = *src;
    ushort4 o;
    o.x = f2bf(v.x); o.y = f2bf(v.y); o.z = f2bf(v.z); o.w = f2bf(v.w);
    *dst = o;
  }
}

// ---------------------------------------------------------------------------
// Gather bucketed embedding rows -> packed bf16 A matrices.
//   Abf layout: [cnt0 x 1024][cnt1 x 256][cnt2 x 64] (+256-row slack)
// ---------------------------------------------------------------------------
__global__ __launch_bounds__(256) void gather_kernel(
    const float* __restrict__ emb0, const float* __restrict__ emb1,
    const float* __restrict__ emb2, const int* __restrict__ cnt,
    const int* __restrict__ blocal, unsigned short* __restrict__ Abf) {
  const int b = blockIdx.x;
  const int c0 = cnt[0], c1 = cnt[1], c2 = cnt[2];
  const float* emb;
  const int* bl;
  int H, count, baseRow, lg;
  size_t off;
  if (b < 4096) {
    emb = emb0; bl = blocal; H = 1024; count = c0; off = 0;
    baseRow = b * 4; lg = 6;
  } else if (b < 5120) {
    emb = emb1; bl = blocal + NMAX; H = 256; count = c1;
    off = (size_t)c0 * 1024; baseRow = (b - 4096) * 16; lg = 4;
  } else {
    emb = emb2; bl = blocal + 2 * NMAX; H = 64; count = c2;
    off = (size_t)c0 * 1024 + (size_t)c1 * 256; baseRow = (b - 5120) * 64; lg = 2;
  }
  const int tid = threadIdx.x;
  const int r = baseRow + (tid >> lg);
  if (r >= count) return;
  const int e = (tid & ((1 << lg) - 1)) * 16;
  const float* src = emb + (size_t)bl[r] * H + e;
  unsigned short* d = Abf + off + (size_t)r * H + e;
  float4 v0 = ((const float4*)src)[0];
  float4 v1 = ((const float4*)src)[1];
  float4 v2 = ((const float4*)src)[2];
  float4 v3 = ((const float4*)src)[3];
  *(short8*)d = cvt8(v0, v1);
  *(short8*)(d + 8) = cvt8(v2, v3);
}

// ---------------------------------------------------------------------------
// Pipelined bf16 MFMA GEMM: BM=256 x BN=128, BK=64, 8 waves (4Mx2N).
// Triple-buffered LDS (3 x 48KB), counted vmcnt (never drains to 0 in the
// steady state), raw s_barrier, setprio around MFMA clusters, and an XOR
// bank-swizzle (b ^= ((b>>7)&3)<<4) applied both-sides: pre-swizzled global
// source for global_load_lds (linear LDS dest) + swizzled ds_read addresses.
// Fragment reads drop from 8-way to 2-way (free) bank aliasing.
// ---------------------------------------------------------------------------
template <int H>
__device__ __forceinline__ void gemm_body(
    const unsigned short* __restrict__ A, const unsigned short* __restrict__ B,
    int count, const int* __restrict__ bucket, float* __restrict__ out,
    char* lds, int* rowTok) {
  const int m0 = blockIdx.y * BM;
  if (m0 >= count) return;
  const int n0 = blockIdx.x * BN;
  constexpr int NT = H / 64;

  const int tid = threadIdx.x;
  const int wave = tid >> 6;
  const int lane = tid & 63;
  const int quad = lane >> 4;
  const int l16 = lane & 15;
  const int wm = wave & 3;   // 4 m-waves: rows [wm*64, wm*64+64)
  const int wn = wave >> 2;  // 2 n-waves: cols [wn*64, wn*64+64)

  if (tid < BM) {
    int m = m0 + tid;
    rowTok[tid] = (m < count) ? bucket[m] : -1;
  }

  // --- staging: per-thread logical slot after the involution -------------
  // linear within-chunk dest byte d = wave*1024 + lane*16; logical slot
  // l = d ^ ((d>>7)&3)<<4  ->  row = l>>6 (0..127), 16B slot = (l>>4)&3.
  const int dl = wave * 1024 + lane * 16;
  const int lswz = dl ^ (((dl >> 7) & 3) << 4);
  const int rW = lswz >> 6;
  const int ckW = (lswz >> 4) & 3;
  const char* Abyte = (const char*)A;
  const char* Bbyte = (const char*)B;
  const size_t aOff0 = ((size_t)(m0 + rW) * H) * 2 + ckW * 16;
  const size_t aOff1 = ((size_t)(m0 + 128 + rW) * H) * 2 + ckW * 16;
  const size_t bOff = ((size_t)(n0 + rW) * H) * 2 + ckW * 16;

  // stage one K-tile (6 x global_load_lds per thread) into buffer `buf`
  auto stage = [&](int kt, char* buf) {
    const int kb = kt * 128;  // 64 k-elems * 2B per K-tile
#pragma unroll
    for (int s = 0; s < 2; ++s) {
      __builtin_amdgcn_global_load_lds(
          (const __attribute__((address_space(1))) void*)(Abyte + aOff0 + kb + s * 64),
          (__attribute__((address_space(3))) void*)(buf + s * 16384 + wave * 1024),
          16, 0, 0);
      __builtin_amdgcn_global_load_lds(
          (const __attribute__((address_space(1))) void*)(Abyte + aOff1 + kb + s * 64),
          (__attribute__((address_space(3))) void*)(buf + s * 16384 + 8192 + wave * 1024),
          16, 0, 0);
      __builtin_amdgcn_global_load_lds(
          (const __attribute__((address_space(1))) void*)(Bbyte + bOff + kb + s * 64),
          (__attribute__((address_space(3))) void*)(buf + BOFFS + s * 8192 + wave * 1024),
          16, 0, 0);
    }
  };

  // --- fragment read offsets (K-invariant, swizzled) ---------------------
  int offA[2][4], offB[2][4];
#pragma unroll
  for (int s = 0; s < 2; ++s) {
#pragma unroll
    for (int i = 0; i < 4; ++i) {
      int ba = (wm * 64 + i * 16 + l16) * 64 + quad * 16;
      offA[s][i] = s * 16384 + (ba ^ (((ba >> 7) & 3) << 4));
      int bb = (wn * 64 + i * 16 + l16) * 64 + quad * 16;
      offB[s][i] = BOFFS + s * 8192 + (bb ^ (((bb >> 7) & 3) << 4));
    }
  }

  // --- prologue: fill the 3-deep pipeline --------------------------------
  if (NT >= 1) stage(0, lds);
  if (NT >= 2) stage(1, lds + LDSBUF);
  if (NT >= 3) stage(2, lds + 2 * LDSBUF);

  floatx4 acc[4][4];
#pragma unroll
  for (int i = 0; i < 4; ++i)
#pragma unroll
    for (int j = 0; j < 4; ++j) acc[i][j] = (floatx4){0.f, 0.f, 0.f, 0.f};

#pragma unroll
  for (int kt = 0; kt < NT; ++kt) {
    // counted wait: K-tile kt's 6 loads landed; up to 12 stay in flight
    const int rem = NT - 1 - kt;
    if (rem >= 2)
      asm volatile("s_waitcnt vmcnt(12)" ::: "memory");
    else if (rem == 1)
      asm volatile("s_waitcnt vmcnt(6)" ::: "memory");
    else
      asm volatile("s_waitcnt vmcnt(0)" ::: "memory");
    asm volatile("s_barrier" ::: "memory");  // all waves' slices landed

    const char* buf = lds + (kt % 3) * LDSBUF;
#pragma unroll
    for (int ph = 0; ph < 4; ++ph) {  // C-quadrant phases
      const int mh = ph >> 1, nh = ph & 1;
      short8 a[2][2], b[2][2];
#pragma unroll
      for (int s = 0; s < 2; ++s)
#pragma unroll
        for (int i = 0; i < 2; ++i) {
          a[s][i] = *(const short8*)(buf + offA[s][mh * 2 + i]);
          b[s][i] = *(const short8*)(buf + offB[s][nh * 2 + i]);
        }
      __builtin_amdgcn_s_setprio(1);
#pragma unroll
      for (int s = 0; s < 2; ++s)
#pragma unroll
        for (int i = 0; i < 2; ++i)
#pragma unroll
          for (int j = 0; j < 2; ++j)
            acc[mh * 2 + i][nh * 2 + j] = __builtin_amdgcn_mfma_f32_16x16x32_bf16(
                a[s][i], b[s][j], acc[mh * 2 + i][nh * 2 + j], 0, 0, 0);
      __builtin_amdgcn_s_setprio(0);
    }
    asm volatile("s_barrier" ::: "memory");  // all reads of buf done
    if (kt + 3 < NT) stage(kt + 3, lds + (kt % 3) * LDSBUF);
  }

  // --- epilogue: scatter rows (C/D: col=lane&15, row=quad*4+reg) ---------
  const int colBase = n0 + wn * 64 + l16;
#pragma unroll
  for (int mi = 0; mi < 4; ++mi) {
#pragma unroll
    for (int r = 0; r < 4; ++r) {
      int tok = rowTok[wm * 64 + mi * 16 + quad * 4 + r];
      if (tok >= 0) {
        float* o = out + (size_t)tok * DOUT + colBase;
#pragma unroll
        for (int ni = 0; ni < 4; ++ni) o[ni * 16] = acc[mi][ni][r];
      }
    }
  }
}

__global__ __launch_bounds__(512, 2) void gemm_pipe(
    const unsigned short* __restrict__ Abf,
    const unsigned short* __restrict__ wb0,
    const unsigned short* __restrict__ wb1,
    const unsigned short* __restrict__ wb2, const int* __restrict__ cnt,
    const int* __restrict__ bucket, float* __restrict__ out) {
  __shared__ __align__(16) char lds[3 * LDSBUF + BM * 4];
  int* rowTok = (int*)(lds + 3 * LDSBUF);

  const int z = blockIdx.z;
  const int c0 = cnt[0];
  const int c1 = cnt[1];
  if (z == 0)
    gemm_body<1024>(Abf, wb0, c0, bucket, out, lds, rowTok);
  else if (z == 1)
    gemm_body<256>(Abf + (size_t)c0 * 1024, wb1, c1, bucket + NMAX, out, lds,
                   rowTok);
  else
    gemm_body<64>(Abf + (size_t)c0 * 1024 + (size_t)c1 * 256, wb2, cnt[2],
                  bucket + 2 * NMAX, out, lds, rowTok);
}

extern "C" void kernel_launch(void* const* d_in, const int* in_sizes, int n_in,
                              void* d_out, int out_size, void* d_ws, size_t ws_size,
                              hipStream_t stream) {
  const int* idx = (const int*)d_in[0];
  const float* emb0 = (const float*)d_in[1];
  const float* w0 = (const float*)d_in[2];
  const float* emb1 = (const float*)d_in[3];
  const float* w1 = (const float*)d_in[4];
  const float* emb2 = (const float*)d_in[5];
  const float* w2 = (const float*)d_in[6];
  float* out = (float*)d_out;
  const int N = in_sizes[0];  // 16384

  // ---- workspace layout ----
  char* ws = (char*)d_ws;
  int* cnt = (int*)ws;                              // 64 B
  int* bucket = (int*)(ws + 1024);                  // 3*NMAX ints
  int* blocal = bucket + 3 * NMAX;                  // 3*NMAX ints
  size_t off = 1024 + (size_t)6 * NMAX * 4;
  off = (off + 255) & ~(size_t)255;
  unsigned short* wb0 = (unsigned short*)(ws + off); off += (size_t)DOUT * 1024 * 2;
  unsigned short* wb1 = (unsigned short*)(ws + off); off += (size_t)DOUT * 256 * 2;
  unsigned short* wb2 = (unsigned short*)(ws + off); off += (size_t)DOUT * 64 * 2;
  off = (off + 255) & ~(size_t)255;
  unsigned short* Abf = (unsigned short*)(ws + off);
  off += (size_t)(NMAX + 256) * 1024 * 2;  // packed A + BM-row tile slack

  hipMemsetAsync(cnt, 0, 16 * sizeof(int), stream);

  // classify (64 blocks) + weight cvt (1344 blocks)
  classify_cvt_kernel<<<64 + 1344, 256, 0, stream>>>(
      idx, cnt, bucket, blocal, N, w0, w1, w2, wb0, wb1, wb2);

  // gather bucketed emb rows -> packed bf16 A
  gather_kernel<<<5376, 256, 0, stream>>>(emb0, emb1, emb2, cnt, blocal, Abf);

  // pipelined GEMM per cluster: z = cluster
  dim3 grid(DOUT / BN, NMAX / BM, 3);
  gemm_pipe<<<grid, 512, 0, stream>>>(Abf, wb0, wb1, wb2, cnt, bucket, out);
}